// Round 1
// baseline (437.728 us; speedup 1.0000x reference)
//
#include <hip/hip_runtime.h>
#include <stdint.h>

typedef __bf16 bf16x8 __attribute__((ext_vector_type(8)));
typedef float f32x4 __attribute__((ext_vector_type(4)));

static __device__ __forceinline__ unsigned short f2bf(float f) {
  unsigned u = __builtin_bit_cast(unsigned, f);
  u += 0x7fffu + ((u >> 16) & 1u);   // RNE
  return (unsigned short)(u >> 16);
}

static __device__ __forceinline__ void gload_lds16(const void* g, void* l) {
  __builtin_amdgcn_global_load_lds(
      (const __attribute__((address_space(1))) unsigned int*)(uintptr_t)g,
      (__attribute__((address_space(3))) unsigned int*)(uintptr_t)l, 16, 0, 0);
}

// ------------------------- fp32 -> bf16 convert -------------------------
__global__ void cvt_bf16(const float* __restrict__ src, unsigned short* __restrict__ dst, int n4) {
  int i = blockIdx.x * blockDim.x + threadIdx.x;
  if (i < n4) {
    float4 f = ((const float4*)src)[i];
    ushort4 o;
    o.x = f2bf(f.x); o.y = f2bf(f.y); o.z = f2bf(f.z); o.w = f2bf(f.w);
    ((ushort4*)dst)[i] = o;
  }
}

// ------------------------- GEMM: C[M,N] = A[M,K] @ W[N,K]^T + bias ------
// M=8192, N=1024, K=1024. A,W bf16 (K-contiguous both). 128x128 tile, BK=64,
// 256 threads = 4 waves (2x2), each wave 64x64 via 4x4 frags of 16x16x32.
// LDS tiles XOR-swizzled (st-style, 16B units): read chunk g of row r lives at
// chunk g^(r&7); staging pre-swizzles the GLOBAL source address (linear LDS
// dest as global_load_lds requires).
#define GM 8192
#define GN 1024
#define GK 1024

template <bool OUTF32>
__global__ __launch_bounds__(256) void gemm_bt(const unsigned short* __restrict__ A,
                                               const unsigned short* __restrict__ Bw,
                                               const float* __restrict__ bias,
                                               void* __restrict__ Cout) {
  __shared__ unsigned short As[128 * 64];
  __shared__ unsigned short Bs[128 * 64];
  const int tid = threadIdx.x;
  const int w = tid >> 6;
  const int lane = tid & 63;
  const int lq = lane & 15;
  const int g = lane >> 4;
  const int bm = blockIdx.y * 128;
  const int bn = blockIdx.x * 128;
  const int srow = lane >> 3;                // 0..7 within the 8-row group
  const int schunk = (lane & 7) ^ srow;      // pre-swizzled source 16B chunk
  const int wrow = (w >> 1) * 64;
  const int wcol = (w & 1) * 64;

  f32x4 acc[4][4] = {};

  for (int kt = 0; kt < GK / 64; ++kt) {
    __syncthreads();                         // prev-iter reads done before overwrite
#pragma unroll
    for (int j = 0; j < 4; ++j) {
      const int r0 = w * 32 + j * 8;         // wave-uniform LDS dest base
      const unsigned short* ag = A  + (size_t)(bm + r0 + srow) * GK + kt * 64 + schunk * 8;
      const unsigned short* bg = Bw + (size_t)(bn + r0 + srow) * GK + kt * 64 + schunk * 8;
      gload_lds16(ag, As + r0 * 64);
      gload_lds16(bg, Bs + r0 * 64);
    }
    __syncthreads();                         // compiler drains vmcnt before barrier
#pragma unroll
    for (int kk = 0; kk < 2; ++kk) {
      bf16x8 af[4], bfv[4];
#pragma unroll
      for (int mt = 0; mt < 4; ++mt) {
        int m = wrow + mt * 16 + lq;
        af[mt] = *(const bf16x8*)&As[m * 64 + ((kk * 32 + g * 8) ^ ((m & 7) << 3))];
      }
#pragma unroll
      for (int nt = 0; nt < 4; ++nt) {
        int n = wcol + nt * 16 + lq;
        bfv[nt] = *(const bf16x8*)&Bs[n * 64 + ((kk * 32 + g * 8) ^ ((n & 7) << 3))];
      }
#pragma unroll
      for (int mt = 0; mt < 4; ++mt)
#pragma unroll
        for (int nt = 0; nt < 4; ++nt)
          acc[mt][nt] = __builtin_amdgcn_mfma_f32_16x16x32_bf16(af[mt], bfv[nt], acc[mt][nt], 0, 0, 0);
    }
  }

  float bvs[4];
#pragma unroll
  for (int nt = 0; nt < 4; ++nt) bvs[nt] = bias[bn + wcol + nt * 16 + lq];

#pragma unroll
  for (int mt = 0; mt < 4; ++mt) {
#pragma unroll
    for (int nt = 0; nt < 4; ++nt) {
#pragma unroll
      for (int r = 0; r < 4; ++r) {
        // C/D layout: row = g*4 + r, col = lq  [measured m89/m91]
        int m = bm + wrow + mt * 16 + g * 4 + r;
        int n = bn + wcol + nt * 16 + lq;
        float v = acc[mt][nt][r] + bvs[nt];
        if (OUTF32) ((float*)Cout)[(size_t)m * GN + n] = v;
        else        ((unsigned short*)Cout)[(size_t)m * GN + n] = f2bf(v);
      }
    }
  }
}

// ------------------------- flash attention --------------------------------
// grid: (32 q-tiles of 64 rows, 64 bh). 256 threads = 4 waves, wave w owns
// q rows [qt*64 + w*16, +16). KVB=64 per step. Swapped QK^T: S^T = mfma(K, Q)
// so each lane's scores share one query (col = lq) -> softmax state per-lane.
// PV computed transposed: O^T = mfma(Vt, P^T), accum per-lane col = q.
__global__ __launch_bounds__(256) void attn_fwd(const unsigned short* __restrict__ Qp,
                                                const unsigned short* __restrict__ Kp,
                                                const unsigned short* __restrict__ Vp,
                                                unsigned short* __restrict__ Op) {
  __shared__ unsigned short Ks[64 * 64];      // [key][d]  swizzled
  __shared__ unsigned short Vt[64 * 64];      // [d][key]  swizzled
  __shared__ unsigned short Pl[4 * 16 * 64];  // per-wave [q][k] swizzled
  const int tid = threadIdx.x;
  const int w = tid >> 6;
  const int lane = tid & 63;
  const int lq = lane & 15;
  const int g = lane >> 4;
  const int qt = blockIdx.x;
  const int bh = blockIdx.y;
  const int b = bh >> 4;
  const int h = bh & 15;
  const size_t rowbase = (size_t)b * 2048;
  const int hcol = h * 64;
  const int srow = lane >> 3;
  const int schunk = (lane & 7) ^ srow;

  // Q fragments (B-operand of mfma(K,Q)): lane holds Q[q=lq, d = kk*32+g*8 ..+7]
  const int qrow = qt * 64 + w * 16 + lq;
  bf16x8 qf[2];
#pragma unroll
  for (int kk = 0; kk < 2; ++kk)
    qf[kk] = *(const bf16x8*)&Qp[(rowbase + qrow) * 1024 + hcol + kk * 32 + g * 8];

  float m_run = -1e30f, lsum = 0.f;
  f32x4 oacc[4] = {};                         // O^T tiles: d = dt*16 + (g*4+r), q = lq
  unsigned short* Pw = Pl + w * 1024;

  for (int j = 0; j < 32; ++j) {
    __syncthreads();
    // stage K tile [64][64] via global_load_lds, source pre-swizzled
#pragma unroll
    for (int rnd = 0; rnd < 2; ++rnd) {
      const int r0 = (w * 2 + rnd) * 8;
      const unsigned short* kg = Kp + (rowbase + j * 64 + r0 + srow) * 1024 + hcol + schunk * 8;
      gload_lds16(kg, Ks + r0 * 64);
    }
    // stage V transposed: Vt[d][key], swizzled, reg-staged (16 elems/thread)
    {
      const int key = tid & 63;
      const int dbase = (tid >> 6) * 8;
#pragma unroll
      for (int rep = 0; rep < 2; ++rep) {
        const int d0 = dbase + rep * 32;
        uint4 u = *(const uint4*)&Vp[(rowbase + j * 64 + key) * 1024 + hcol + d0];
        unsigned short e[8] = {(unsigned short)(u.x & 0xffff), (unsigned short)(u.x >> 16),
                               (unsigned short)(u.y & 0xffff), (unsigned short)(u.y >> 16),
                               (unsigned short)(u.z & 0xffff), (unsigned short)(u.z >> 16),
                               (unsigned short)(u.w & 0xffff), (unsigned short)(u.w >> 16)};
#pragma unroll
        for (int t2 = 0; t2 < 8; ++t2) {
          int d = d0 + t2;
          Vt[d * 64 + (key ^ ((d & 7) << 3))] = e[t2];
        }
      }
    }
    __syncthreads();

    // S^T tiles: tile t covers keys [t*16, t*16+16). lane holds keys t*16+g*4+r, query lq.
    float s[4][4];
#pragma unroll
    for (int t = 0; t < 4; ++t) {
      f32x4 c = {};
#pragma unroll
      for (int kk = 0; kk < 2; ++kk) {
        int krow = t * 16 + lq;
        bf16x8 kf = *(const bf16x8*)&Ks[krow * 64 + ((kk * 32 + g * 8) ^ ((krow & 7) << 3))];
        c = __builtin_amdgcn_mfma_f32_16x16x32_bf16(kf, qf[kk], c, 0, 0, 0);
      }
#pragma unroll
      for (int r = 0; r < 4; ++r) s[t][r] = c[r] * 0.125f;   // 1/sqrt(64)
    }

    // online softmax: reduce over the 4 lane-groups sharing query lq
    float tmax = s[0][0];
#pragma unroll
    for (int t = 0; t < 4; ++t)
#pragma unroll
      for (int r = 0; r < 4; ++r) tmax = fmaxf(tmax, s[t][r]);
    tmax = fmaxf(tmax, __shfl_xor(tmax, 16));
    tmax = fmaxf(tmax, __shfl_xor(tmax, 32));
    float mnew = fmaxf(m_run, tmax);
    float corr = __expf(m_run - mnew);
    float psum = 0.f;
#pragma unroll
    for (int t = 0; t < 4; ++t) {
      float p0 = __expf(s[t][0] - mnew);
      float p1 = __expf(s[t][1] - mnew);
      float p2 = __expf(s[t][2] - mnew);
      float p3 = __expf(s[t][3] - mnew);
      psum += (p0 + p1) + (p2 + p3);
      ushort4 pk;
      pk.x = f2bf(p0); pk.y = f2bf(p1); pk.z = f2bf(p2); pk.w = f2bf(p3);
      // P[q=lq][k = t*16+g*4 .. +3], swizzled at 8-ushort granularity
      *(ushort4*)&Pw[lq * 64 + ((t * 16 + g * 4) ^ ((lq & 7) << 3))] = pk;
    }
    lsum = lsum * corr + psum;
    m_run = mnew;
#pragma unroll
    for (int dt = 0; dt < 4; ++dt) oacc[dt] *= corr;

    // PV: O^T[d, q] += sum_k Vt[d,k] * P^T[k,q]; P^T B-frag read per kk, reused over dt
    bf16x8 pf[2];
#pragma unroll
    for (int kk = 0; kk < 2; ++kk)
      pf[kk] = *(const bf16x8*)&Pw[lq * 64 + ((kk * 32 + g * 8) ^ ((lq & 7) << 3))];
#pragma unroll
    for (int dt = 0; dt < 4; ++dt) {
#pragma unroll
      for (int kk = 0; kk < 2; ++kk) {
        int d = dt * 16 + lq;
        bf16x8 vf = *(const bf16x8*)&Vt[d * 64 + ((kk * 32 + g * 8) ^ ((d & 7) << 3))];
        oacc[dt] = __builtin_amdgcn_mfma_f32_16x16x32_bf16(vf, pf[kk], oacc[dt], 0, 0, 0);
      }
    }
  }

  lsum += __shfl_xor(lsum, 16);
  lsum += __shfl_xor(lsum, 32);
  float inv = 1.0f / lsum;
#pragma unroll
  for (int dt = 0; dt < 4; ++dt) {
    ushort4 pk;
    pk.x = f2bf(oacc[dt][0] * inv);
    pk.y = f2bf(oacc[dt][1] * inv);
    pk.z = f2bf(oacc[dt][2] * inv);
    pk.w = f2bf(oacc[dt][3] * inv);
    *(ushort4*)&Op[(rowbase + qt * 64 + w * 16 + lq) * 1024 + hcol + dt * 16 + g * 4] = pk;
  }
}

// ------------------------- launcher --------------------------------------
extern "C" void kernel_launch(void* const* d_in, const int* in_sizes, int n_in,
                              void* d_out, int out_size, void* d_ws, size_t ws_size,
                              hipStream_t stream) {
  const float* q  = (const float*)d_in[0];
  const float* k  = (const float*)d_in[1];
  const float* v  = (const float*)d_in[2];
  const float* Wq = (const float*)d_in[3];
  const float* bq = (const float*)d_in[4];
  const float* Wk = (const float*)d_in[5];
  const float* bk = (const float*)d_in[6];
  const float* Wv = (const float*)d_in[7];
  const float* bv = (const float*)d_in[8];
  const float* Wo = (const float*)d_in[9];
  const float* bo = (const float*)d_in[10];

  unsigned short* ws = (unsigned short*)d_ws;
  const size_t SZ  = (size_t)8192 * 1024;
  const size_t WSZ = (size_t)1024 * 1024;
  unsigned short* Xq  = ws;
  unsigned short* Xk  = Xq + SZ;
  unsigned short* Xv  = Xk + SZ;
  unsigned short* Wqb = Xv + SZ;
  unsigned short* Wkb = Wqb + WSZ;
  unsigned short* Wvb = Wkb + WSZ;
  unsigned short* Wob = Wvb + WSZ;
  unsigned short* Qp  = Wob + WSZ;
  unsigned short* Kp  = Qp + SZ;
  unsigned short* Vp  = Kp + SZ;
  unsigned short* At  = Xq;   // Xq dead after Q projection -> reuse for attn out

  cvt_bf16<<<(int)(SZ / 4 / 256), 256, 0, stream>>>(q,  Xq,  (int)(SZ / 4));
  cvt_bf16<<<(int)(SZ / 4 / 256), 256, 0, stream>>>(k,  Xk,  (int)(SZ / 4));
  cvt_bf16<<<(int)(SZ / 4 / 256), 256, 0, stream>>>(v,  Xv,  (int)(SZ / 4));
  cvt_bf16<<<(int)(WSZ / 4 / 256), 256, 0, stream>>>(Wq, Wqb, (int)(WSZ / 4));
  cvt_bf16<<<(int)(WSZ / 4 / 256), 256, 0, stream>>>(Wk, Wkb, (int)(WSZ / 4));
  cvt_bf16<<<(int)(WSZ / 4 / 256), 256, 0, stream>>>(Wv, Wvb, (int)(WSZ / 4));
  cvt_bf16<<<(int)(WSZ / 4 / 256), 256, 0, stream>>>(Wo, Wob, (int)(WSZ / 4));

  dim3 ggrid(GN / 128, GM / 128);
  gemm_bt<false><<<ggrid, 256, 0, stream>>>(Xq, Wqb, bq, Qp);
  gemm_bt<false><<<ggrid, 256, 0, stream>>>(Xk, Wkb, bk, Kp);
  gemm_bt<false><<<ggrid, 256, 0, stream>>>(Xv, Wvb, bv, Vp);

  attn_fwd<<<dim3(32, 64), 256, 0, stream>>>(Qp, Kp, Vp, At);

  gemm_bt<true><<<ggrid, 256, 0, stream>>>(At, Wob, bo, (float*)d_out);
}

// Round 2
// 358.179 us; speedup vs baseline: 1.2221x; 1.2221x over previous
//
#include <hip/hip_runtime.h>
#include <stdint.h>

typedef __bf16 bf16x8 __attribute__((ext_vector_type(8)));
typedef __bf16 bf16x4 __attribute__((ext_vector_type(4)));
typedef float f32x4 __attribute__((ext_vector_type(4)));

static __device__ __forceinline__ unsigned short f2bf(float f) {
  unsigned u = __builtin_bit_cast(unsigned, f);
  u += 0x7fffu + ((u >> 16) & 1u);   // RNE
  return (unsigned short)(u >> 16);
}

static __device__ __forceinline__ unsigned short bfu(float x) {
  __bf16 b = (__bf16)x;
  return __builtin_bit_cast(unsigned short, b);
}

#if __has_builtin(__builtin_amdgcn_exp2f)
#define EXP2(x) __builtin_amdgcn_exp2f(x)
#else
#define EXP2(x) __expf(0.69314718055994531f * (x))
#endif

static __device__ __forceinline__ void gload_lds16(const void* g, void* l) {
  __builtin_amdgcn_global_load_lds(
      (const __attribute__((address_space(1))) unsigned int*)(uintptr_t)g,
      (__attribute__((address_space(3))) unsigned int*)(uintptr_t)l, 16, 0, 0);
}

// ------------------------- fused fp32 -> bf16 convert (all 7 tensors) ----
// dst layout: [q(8.4M) | k | v | wq(1.05M) | wk | wv | wo] in float4 units.
#define BIGU 2097152
#define WU   262144
__global__ __launch_bounds__(256) void cvt_all(const float* __restrict__ q,  const float* __restrict__ k,
                                               const float* __restrict__ v,  const float* __restrict__ wq,
                                               const float* __restrict__ wk, const float* __restrict__ wv,
                                               const float* __restrict__ wo, ushort4* __restrict__ dst) {
  int u = blockIdx.x * 256 + threadIdx.x;
  const float4* src;
  if (u < BIGU)            src = (const float4*)q + u;
  else if (u < 2 * BIGU)   src = (const float4*)k + (u - BIGU);
  else if (u < 3 * BIGU)   src = (const float4*)v + (u - 2 * BIGU);
  else {
    int r = u - 3 * BIGU;
    if (r < WU)            src = (const float4*)wq + r;
    else if (r < 2 * WU)   src = (const float4*)wk + (r - WU);
    else if (r < 3 * WU)   src = (const float4*)wv + (r - 2 * WU);
    else                   src = (const float4*)wo + (r - 3 * WU);
  }
  float4 f = *src;
  ushort4 o;
  o.x = f2bf(f.x); o.y = f2bf(f.y); o.z = f2bf(f.z); o.w = f2bf(f.w);
  dst[u] = o;
}

// ------------------------- GEMM: C[M,N] = A[M,K] @ W[N,K]^T + bias ------
#define GM 8192
#define GN 1024
#define GK 1024

template <bool OUTF32>
__global__ __launch_bounds__(256) void gemm_bt(const unsigned short* __restrict__ A,
                                               const unsigned short* __restrict__ Bw,
                                               const float* __restrict__ bias,
                                               void* __restrict__ Cout) {
  __shared__ unsigned short As[128 * 64];
  __shared__ unsigned short Bs[128 * 64];
  const int tid = threadIdx.x;
  const int w = tid >> 6;
  const int lane = tid & 63;
  const int lq = lane & 15;
  const int g = lane >> 4;
  const int bm = blockIdx.y * 128;
  const int bn = blockIdx.x * 128;
  const int srow = lane >> 3;
  const int schunk = (lane & 7) ^ srow;
  const int wrow = (w >> 1) * 64;
  const int wcol = (w & 1) * 64;

  f32x4 acc[4][4] = {};

  for (int kt = 0; kt < GK / 64; ++kt) {
    __syncthreads();
#pragma unroll
    for (int j = 0; j < 4; ++j) {
      const int r0 = w * 32 + j * 8;
      const unsigned short* ag = A  + (size_t)(bm + r0 + srow) * GK + kt * 64 + schunk * 8;
      const unsigned short* bg = Bw + (size_t)(bn + r0 + srow) * GK + kt * 64 + schunk * 8;
      gload_lds16(ag, As + r0 * 64);
      gload_lds16(bg, Bs + r0 * 64);
    }
    __syncthreads();
#pragma unroll
    for (int kk = 0; kk < 2; ++kk) {
      bf16x8 af[4], bfv[4];
#pragma unroll
      for (int mt = 0; mt < 4; ++mt) {
        int m = wrow + mt * 16 + lq;
        af[mt] = *(const bf16x8*)&As[m * 64 + ((kk * 32 + g * 8) ^ ((m & 7) << 3))];
      }
#pragma unroll
      for (int nt = 0; nt < 4; ++nt) {
        int n = wcol + nt * 16 + lq;
        bfv[nt] = *(const bf16x8*)&Bs[n * 64 + ((kk * 32 + g * 8) ^ ((n & 7) << 3))];
      }
#pragma unroll
      for (int mt = 0; mt < 4; ++mt)
#pragma unroll
        for (int nt = 0; nt < 4; ++nt)
          acc[mt][nt] = __builtin_amdgcn_mfma_f32_16x16x32_bf16(af[mt], bfv[nt], acc[mt][nt], 0, 0, 0);
    }
  }

  float bvs[4];
#pragma unroll
  for (int nt = 0; nt < 4; ++nt) bvs[nt] = bias[bn + wcol + nt * 16 + lq];

#pragma unroll
  for (int mt = 0; mt < 4; ++mt) {
#pragma unroll
    for (int nt = 0; nt < 4; ++nt) {
#pragma unroll
      for (int r = 0; r < 4; ++r) {
        int m = bm + wrow + mt * 16 + g * 4 + r;
        int n = bn + wcol + nt * 16 + lq;
        float v = acc[mt][nt][r] + bvs[nt];
        if (OUTF32) ((float*)Cout)[(size_t)m * GN + n] = v;
        else        ((unsigned short*)Cout)[(size_t)m * GN + n] = f2bf(v);
      }
    }
  }
}

// ------------------------- flash attention v2 ----------------------------
// grid (16 q-tiles of 128 rows, 64 bh), 256 threads = 4 waves, each wave 32
// q-rows as two 16-row halves. KVB=64, double-buffered K (row-swizzled) and
// V (tr16-subtiled) staged via global_load_lds with pre-swizzled source.
// Swapped QK^T (S^T = mfma(K,Q)); PV via ds_read_b64_tr_b16 V-fragments;
// P per-wave LDS round trip; defer-max (THR=64 raw = 8 scaled).
#define TRRD(dst, off) \
  asm volatile("ds_read_b64_tr_b16 %0, %1 offset:" off \
               : "=v"(dst) \
               : "v"((const __attribute__((address_space(3))) unsigned short*)(uintptr_t)vb))

__global__ __launch_bounds__(256, 3) void attn_fwd(const unsigned short* __restrict__ Qp,
                                                   const unsigned short* __restrict__ Kp,
                                                   const unsigned short* __restrict__ Vp,
                                                   unsigned short* __restrict__ Op) {
  __shared__ unsigned short Ks[2][4096];   // [key][d] row-swizzled, 8KB each
  __shared__ unsigned short Vs[2][4096];   // [key/4][d/16][4][16] subtiled, 8KB each
  __shared__ unsigned short Pl[8][1024];   // per (wave, q-half): [16 q][64 k] swizzled
  const int tid = threadIdx.x;
  const int w = tid >> 6;
  const int lane = tid & 63;
  const int lq = lane & 15;
  const int g = lane >> 4;
  const int qt = blockIdx.x;
  const int bh = blockIdx.y;
  const int b = bh >> 4;
  const int h = bh & 15;
  const size_t rowbase = (size_t)b * 2048;
  const int hcol = h * 64;

  const int c0 = w * 2, c1 = w * 2 + 1;          // two staging calls per wave
  const int srow = lane >> 3;
  const int schunk = (lane & 7) ^ srow;          // K row-swizzle source chunk
  // V subtile staging inverse map: call c, lane i -> (key, d0)
  const int vkeyl = (lane >> 5) * 4 + ((lane >> 1) & 3);
  const int vd0   = ((lane >> 3) & 3) * 16 + (lane & 1) * 8;

  const unsigned short* kq = Kp + rowbase * 1024 + hcol;
  const unsigned short* vq = Vp + rowbase * 1024 + hcol;

  // Q fragments: two q-halves
  bf16x8 qf[2][2];
#pragma unroll
  for (int qh = 0; qh < 2; ++qh) {
    const int qrow = qt * 128 + w * 32 + qh * 16 + lq;
#pragma unroll
    for (int kk = 0; kk < 2; ++kk)
      qf[qh][kk] = *(const bf16x8*)&Qp[(rowbase + qrow) * 1024 + hcol + kk * 32 + g * 8];
  }

  const float ks2 = 0.125f * 1.44269504088896f;  // scale * log2(e)
  float m0 = -1e30f, m1 = -1e30f, l0 = 0.f, l1 = 0.f;
  f32x4 oa[2][4] = {};
  unsigned short* Pw0 = Pl[w * 2];
  unsigned short* Pw1 = Pl[w * 2 + 1];
  const int pxor = (lq & 7) << 3;                // P swizzle (lane const)
  const int kxor = pxor;                         // K row swizzle term (krow&7 == lq&7)

  // prologue: stage tile 0 into buf 0
  {
    gload_lds16(kq + (size_t)(c0 * 8 + srow) * 1024 + schunk * 8, &Ks[0][c0 * 512]);
    gload_lds16(kq + (size_t)(c1 * 8 + srow) * 1024 + schunk * 8, &Ks[0][c1 * 512]);
    gload_lds16(vq + (size_t)(c0 * 8 + vkeyl) * 1024 + vd0, &Vs[0][c0 * 512]);
    gload_lds16(vq + (size_t)(c1 * 8 + vkeyl) * 1024 + vd0, &Vs[0][c1 * 512]);
  }
  __syncthreads();

  for (int j = 0; j < 32; ++j) {
    const int cur = j & 1;
    if (j < 31) {           // issue next tile's staging into other buffer
      const size_t so = (size_t)(j + 1) * 64 * 1024;
      gload_lds16(kq + so + (size_t)(c0 * 8 + srow) * 1024 + schunk * 8, &Ks[cur ^ 1][c0 * 512]);
      gload_lds16(kq + so + (size_t)(c1 * 8 + srow) * 1024 + schunk * 8, &Ks[cur ^ 1][c1 * 512]);
      gload_lds16(vq + so + (size_t)(c0 * 8 + vkeyl) * 1024 + vd0, &Vs[cur ^ 1][c0 * 512]);
      gload_lds16(vq + so + (size_t)(c1 * 8 + vkeyl) * 1024 + vd0, &Vs[cur ^ 1][c1 * 512]);
    }

    // ---- QK^T: S^T tile t = keys [t*16, t*16+16), both q-halves share kf
    f32x4 cc[2][4];
#pragma unroll
    for (int qh = 0; qh < 2; ++qh)
#pragma unroll
      for (int t = 0; t < 4; ++t) cc[qh][t] = (f32x4){0.f, 0.f, 0.f, 0.f};
#pragma unroll
    for (int t = 0; t < 4; ++t) {
      const int rb = (t * 16 + lq) * 64;
#pragma unroll
      for (int kk = 0; kk < 2; ++kk) {
        bf16x8 kf = *(const bf16x8*)&Ks[cur][rb + ((kk * 32 + g * 8) ^ kxor)];
        cc[0][t] = __builtin_amdgcn_mfma_f32_16x16x32_bf16(kf, qf[0][kk], cc[0][t], 0, 0, 0);
        cc[1][t] = __builtin_amdgcn_mfma_f32_16x16x32_bf16(kf, qf[1][kk], cc[1][t], 0, 0, 0);
      }
    }

    // ---- online softmax (raw scores; scale folded into exp2)
    float t0 = cc[0][0][0], t1 = cc[1][0][0];
#pragma unroll
    for (int t = 0; t < 4; ++t)
#pragma unroll
      for (int r = 0; r < 4; ++r) {
        t0 = fmaxf(t0, cc[0][t][r]);
        t1 = fmaxf(t1, cc[1][t][r]);
      }
    t0 = fmaxf(t0, __shfl_xor(t0, 16)); t0 = fmaxf(t0, __shfl_xor(t0, 32));
    t1 = fmaxf(t1, __shfl_xor(t1, 16)); t1 = fmaxf(t1, __shfl_xor(t1, 32));

    const int defer = (t0 - m0 <= 64.f) && (t1 - m1 <= 64.f);
    if (!__all(defer)) {
      float n0 = fmaxf(m0, t0), n1 = fmaxf(m1, t1);
      float cr0 = EXP2(ks2 * (m0 - n0)), cr1 = EXP2(ks2 * (m1 - n1));
      l0 *= cr0; l1 *= cr1;
#pragma unroll
      for (int dt = 0; dt < 4; ++dt) { oa[0][dt] *= cr0; oa[1][dt] *= cr1; }
      m0 = n0; m1 = n1;
    }
    const float mk0 = m0 * ks2, mk1 = m1 * ks2;
    float ps0 = 0.f, ps1 = 0.f;
#pragma unroll
    for (int t = 0; t < 4; ++t) {
      float a0 = EXP2(__builtin_fmaf(cc[0][t][0], ks2, -mk0));
      float a1 = EXP2(__builtin_fmaf(cc[0][t][1], ks2, -mk0));
      float a2 = EXP2(__builtin_fmaf(cc[0][t][2], ks2, -mk0));
      float a3 = EXP2(__builtin_fmaf(cc[0][t][3], ks2, -mk0));
      ps0 += (a0 + a1) + (a2 + a3);
      ushort4 pk0; pk0.x = bfu(a0); pk0.y = bfu(a1); pk0.z = bfu(a2); pk0.w = bfu(a3);
      *(ushort4*)&Pw0[lq * 64 + ((t * 16 + g * 4) ^ pxor)] = pk0;
      float b0 = EXP2(__builtin_fmaf(cc[1][t][0], ks2, -mk1));
      float b1 = EXP2(__builtin_fmaf(cc[1][t][1], ks2, -mk1));
      float b2 = EXP2(__builtin_fmaf(cc[1][t][2], ks2, -mk1));
      float b3 = EXP2(__builtin_fmaf(cc[1][t][3], ks2, -mk1));
      ps1 += (b0 + b1) + (b2 + b3);
      ushort4 pk1; pk1.x = bfu(b0); pk1.y = bfu(b1); pk1.z = bfu(b2); pk1.w = bfu(b3);
      *(ushort4*)&Pw1[lq * 64 + ((t * 16 + g * 4) ^ pxor)] = pk1;
    }
    l0 += ps0; l1 += ps1;

    // ---- PV: O^T += mfma(V^T frag, P^T frag); V frags via hw transpose read
    bf16x8 pf[2][2];
#pragma unroll
    for (int qh = 0; qh < 2; ++qh) {
      unsigned short* Pw = qh ? Pw1 : Pw0;
#pragma unroll
      for (int kk = 0; kk < 2; ++kk)
        pf[qh][kk] = *(const bf16x8*)&Pw[lq * 64 + ((kk * 32 + g * 8) ^ pxor)];
    }
    const unsigned short* vb =
        &Vs[cur][g * 512 + ((lane >> 2) & 3) * 16 + (lane & 3) * 4];
    bf16x4 T[16];
    TRRD(T[0],  "0");    TRRD(T[1],  "128");  TRRD(T[2],  "256");  TRRD(T[3],  "384");
    TRRD(T[4],  "512");  TRRD(T[5],  "640");  TRRD(T[6],  "768");  TRRD(T[7],  "896");
    TRRD(T[8],  "4096"); TRRD(T[9],  "4224"); TRRD(T[10], "4352"); TRRD(T[11], "4480");
    TRRD(T[12], "4608"); TRRD(T[13], "4736"); TRRD(T[14], "4864"); TRRD(T[15], "4992");
    asm volatile("s_waitcnt lgkmcnt(0)" ::: "memory");
    __builtin_amdgcn_sched_barrier(0);
#pragma unroll
    for (int kk = 0; kk < 2; ++kk) {
#pragma unroll
      for (int dt = 0; dt < 4; ++dt) {
        bf16x8 vf = __builtin_shufflevector(T[kk * 8 + dt], T[kk * 8 + 4 + dt],
                                            0, 1, 2, 3, 4, 5, 6, 7);
        oa[0][dt] = __builtin_amdgcn_mfma_f32_16x16x32_bf16(vf, pf[0][kk], oa[0][dt], 0, 0, 0);
        oa[1][dt] = __builtin_amdgcn_mfma_f32_16x16x32_bf16(vf, pf[1][kk], oa[1][dt], 0, 0, 0);
      }
    }
    __syncthreads();
  }

  // ---- epilogue
  l0 += __shfl_xor(l0, 16); l0 += __shfl_xor(l0, 32);
  l1 += __shfl_xor(l1, 16); l1 += __shfl_xor(l1, 32);
  float inv0 = 1.0f / l0, inv1 = 1.0f / l1;
#pragma unroll
  for (int qh = 0; qh < 2; ++qh) {
    const float inv = qh ? inv1 : inv0;
    const int qrow = qt * 128 + w * 32 + qh * 16 + lq;
#pragma unroll
    for (int dt = 0; dt < 4; ++dt) {
      ushort4 pk;
      pk.x = bfu(oa[qh][dt][0] * inv);
      pk.y = bfu(oa[qh][dt][1] * inv);
      pk.z = bfu(oa[qh][dt][2] * inv);
      pk.w = bfu(oa[qh][dt][3] * inv);
      *(ushort4*)&Op[(rowbase + qrow) * 1024 + hcol + dt * 16 + g * 4] = pk;
    }
  }
}

// ------------------------- launcher --------------------------------------
extern "C" void kernel_launch(void* const* d_in, const int* in_sizes, int n_in,
                              void* d_out, int out_size, void* d_ws, size_t ws_size,
                              hipStream_t stream) {
  const float* q  = (const float*)d_in[0];
  const float* k  = (const float*)d_in[1];
  const float* v  = (const float*)d_in[2];
  const float* Wq = (const float*)d_in[3];
  const float* bq = (const float*)d_in[4];
  const float* Wk = (const float*)d_in[5];
  const float* bk = (const float*)d_in[6];
  const float* Wv = (const float*)d_in[7];
  const float* bv = (const float*)d_in[8];
  const float* Wo = (const float*)d_in[9];
  const float* bo = (const float*)d_in[10];

  unsigned short* ws = (unsigned short*)d_ws;
  const size_t SZ  = (size_t)8192 * 1024;
  const size_t WSZ = (size_t)1024 * 1024;
  unsigned short* Xq  = ws;
  unsigned short* Xk  = Xq + SZ;
  unsigned short* Xv  = Xk + SZ;
  unsigned short* Wqb = Xv + SZ;
  unsigned short* Wkb = Wqb + WSZ;
  unsigned short* Wvb = Wkb + WSZ;
  unsigned short* Wob = Wvb + WSZ;
  unsigned short* Qp  = Wob + WSZ;
  unsigned short* Kp  = Qp + SZ;
  unsigned short* Vp  = Kp + SZ;
  unsigned short* At  = Xq;   // Xq dead after Q projection -> reuse

  cvt_all<<<(3 * BIGU + 4 * WU) / 256, 256, 0, stream>>>(q, k, v, Wq, Wk, Wv, Wo, (ushort4*)ws);

  dim3 ggrid(GN / 128, GM / 128);
  gemm_bt<false><<<ggrid, 256, 0, stream>>>(Xq, Wqb, bq, Qp);
  gemm_bt<false><<<ggrid, 256, 0, stream>>>(Xk, Wkb, bk, Kp);
  gemm_bt<false><<<ggrid, 256, 0, stream>>>(Xv, Wvb, bv, Vp);

  attn_fwd<<<dim3(16, 64), 256, 0, stream>>>(Qp, Kp, Vp, At);

  gemm_bt<true><<<ggrid, 256, 0, stream>>>(At, Wob, bo, (float*)d_out);
}

// Round 3
// 353.827 us; speedup vs baseline: 1.2371x; 1.0123x over previous
//
#include <hip/hip_runtime.h>
#include <stdint.h>

typedef __bf16 bf16x8 __attribute__((ext_vector_type(8)));
typedef __bf16 bf16x4 __attribute__((ext_vector_type(4)));
typedef float f32x4 __attribute__((ext_vector_type(4)));

static __device__ __forceinline__ unsigned short f2bf(float f) {
  unsigned u = __builtin_bit_cast(unsigned, f);
  u += 0x7fffu + ((u >> 16) & 1u);   // RNE
  return (unsigned short)(u >> 16);
}

static __device__ __forceinline__ unsigned short bfu(float x) {
  __bf16 b = (__bf16)x;
  return __builtin_bit_cast(unsigned short, b);
}

#if __has_builtin(__builtin_amdgcn_exp2f)
#define EXP2(x) __builtin_amdgcn_exp2f(x)
#else
#define EXP2(x) __expf(0.69314718055994531f * (x))
#endif

static __device__ __forceinline__ void gload_lds16(const void* g, void* l) {
  __builtin_amdgcn_global_load_lds(
      (const __attribute__((address_space(1))) unsigned int*)(uintptr_t)g,
      (__attribute__((address_space(3))) unsigned int*)(uintptr_t)l, 16, 0, 0);
}

// ------------------------- fused fp32 -> bf16 convert (all 7 tensors) ----
#define BIGU 2097152
#define WU   262144
__global__ __launch_bounds__(256) void cvt_all(const float* __restrict__ q,  const float* __restrict__ k,
                                               const float* __restrict__ v,  const float* __restrict__ wq,
                                               const float* __restrict__ wk, const float* __restrict__ wv,
                                               const float* __restrict__ wo, ushort4* __restrict__ dst) {
  int u = blockIdx.x * 256 + threadIdx.x;
  const float4* src;
  if (u < BIGU)            src = (const float4*)q + u;
  else if (u < 2 * BIGU)   src = (const float4*)k + (u - BIGU);
  else if (u < 3 * BIGU)   src = (const float4*)v + (u - 2 * BIGU);
  else {
    int r = u - 3 * BIGU;
    if (r < WU)            src = (const float4*)wq + r;
    else if (r < 2 * WU)   src = (const float4*)wk + (r - WU);
    else if (r < 3 * WU)   src = (const float4*)wv + (r - 2 * WU);
    else                   src = (const float4*)wo + (r - 3 * WU);
  }
  float4 f = *src;
  ushort4 o;
  o.x = f2bf(f.x); o.y = f2bf(f.y); o.z = f2bf(f.z); o.w = f2bf(f.w);
  dst[u] = o;
}

// ------------------------- GEMM: C[M,N] = A[M,K] @ W[N,K]^T + bias ------
// 128x128 tile, BK=64, 2-phase double-buffered prefetch: issue next tile's
// global_load_lds BEFORE compute; single barrier per K-step (compiler's
// vmcnt(0) drain lands after the MFMA cluster). TRIPLE: blockIdx.z picks
// one of the Q/K/V projection triples (contiguous A/W/C arrays).
#define GM 8192
#define GN 1024
#define GK 1024

template <bool OUTF32, bool TRIPLE>
__global__ __launch_bounds__(256, 2) void gemm_bt(const unsigned short* __restrict__ A0,
                                                  const unsigned short* __restrict__ W0,
                                                  const float* __restrict__ bias0,
                                                  const float* __restrict__ bias1,
                                                  const float* __restrict__ bias2,
                                                  void* __restrict__ Cout) {
  __shared__ unsigned short As[2][128 * 64];
  __shared__ unsigned short Bs[2][128 * 64];
  const int z = TRIPLE ? blockIdx.z : 0;
  const unsigned short* A  = A0 + (size_t)z * ((size_t)GM * GK);
  const unsigned short* Bw = W0 + (size_t)z * ((size_t)GN * GK);
  const float* bias = TRIPLE ? (z == 0 ? bias0 : (z == 1 ? bias1 : bias2)) : bias0;

  const int tid = threadIdx.x;
  const int w = tid >> 6;
  const int lane = tid & 63;
  const int lq = lane & 15;
  const int g = lane >> 4;
  const int bm = blockIdx.y * 128;
  const int bn = blockIdx.x * 128;
  const int srow = lane >> 3;
  const int schunk = (lane & 7) ^ srow;
  const int wrow = (w >> 1) * 64;
  const int wcol = (w & 1) * 64;

  f32x4 acc[4][4] = {};

#define STAGE(ktv, bufv)                                                                   \
  do {                                                                                     \
    _Pragma("unroll") for (int j = 0; j < 4; ++j) {                                        \
      const int r0 = w * 32 + j * 8;                                                       \
      gload_lds16(A  + (size_t)(bm + r0 + srow) * GK + (ktv) * 64 + schunk * 8,            \
                  &As[bufv][r0 * 64]);                                                     \
      gload_lds16(Bw + (size_t)(bn + r0 + srow) * GK + (ktv) * 64 + schunk * 8,            \
                  &Bs[bufv][r0 * 64]);                                                     \
    }                                                                                      \
  } while (0)

  STAGE(0, 0);
  __syncthreads();

  for (int kt = 0; kt < GK / 64; ++kt) {
    const int cur = kt & 1;
    if (kt < GK / 64 - 1) STAGE(kt + 1, cur ^ 1);   // prefetch next tile

#pragma unroll
    for (int kk = 0; kk < 2; ++kk) {
      bf16x8 af[4], bfv[4];
#pragma unroll
      for (int mt = 0; mt < 4; ++mt) {
        int m = wrow + mt * 16 + lq;
        af[mt] = *(const bf16x8*)&As[cur][m * 64 + ((kk * 32 + g * 8) ^ ((m & 7) << 3))];
      }
#pragma unroll
      for (int nt = 0; nt < 4; ++nt) {
        int n = wcol + nt * 16 + lq;
        bfv[nt] = *(const bf16x8*)&Bs[cur][n * 64 + ((kk * 32 + g * 8) ^ ((n & 7) << 3))];
      }
#pragma unroll
      for (int mt = 0; mt < 4; ++mt)
#pragma unroll
        for (int nt = 0; nt < 4; ++nt)
          acc[mt][nt] = __builtin_amdgcn_mfma_f32_16x16x32_bf16(af[mt], bfv[nt], acc[mt][nt], 0, 0, 0);
    }
    __syncthreads();   // drains prefetch vmcnt AFTER compute; guards buffer reuse
  }
#undef STAGE

  float bvs[4];
#pragma unroll
  for (int nt = 0; nt < 4; ++nt) bvs[nt] = bias[bn + wcol + nt * 16 + lq];

#pragma unroll
  for (int mt = 0; mt < 4; ++mt) {
#pragma unroll
    for (int nt = 0; nt < 4; ++nt) {
#pragma unroll
      for (int r = 0; r < 4; ++r) {
        int m = bm + wrow + mt * 16 + g * 4 + r;
        int n = bn + wcol + nt * 16 + lq;
        float v = acc[mt][nt][r] + bvs[nt];
        if (OUTF32) ((float*)Cout)[(size_t)m * GN + n] = v;
        else ((unsigned short*)Cout)[(size_t)z * ((size_t)GM * GN) + (size_t)m * GN + n] = f2bf(v);
      }
    }
  }
}

// ------------------------- flash attention (unchanged from r2) -----------
#define TRRD(dst, off) \
  asm volatile("ds_read_b64_tr_b16 %0, %1 offset:" off \
               : "=v"(dst) \
               : "v"((const __attribute__((address_space(3))) unsigned short*)(uintptr_t)vb))

__global__ __launch_bounds__(256, 3) void attn_fwd(const unsigned short* __restrict__ Qp,
                                                   const unsigned short* __restrict__ Kp,
                                                   const unsigned short* __restrict__ Vp,
                                                   unsigned short* __restrict__ Op) {
  __shared__ unsigned short Ks[2][4096];
  __shared__ unsigned short Vs[2][4096];
  __shared__ unsigned short Pl[8][1024];
  const int tid = threadIdx.x;
  const int w = tid >> 6;
  const int lane = tid & 63;
  const int lq = lane & 15;
  const int g = lane >> 4;
  const int qt = blockIdx.x;
  const int bh = blockIdx.y;
  const int b = bh >> 4;
  const int h = bh & 15;
  const size_t rowbase = (size_t)b * 2048;
  const int hcol = h * 64;

  const int c0 = w * 2, c1 = w * 2 + 1;
  const int srow = lane >> 3;
  const int schunk = (lane & 7) ^ srow;
  const int vkeyl = (lane >> 5) * 4 + ((lane >> 1) & 3);
  const int vd0   = ((lane >> 3) & 3) * 16 + (lane & 1) * 8;

  const unsigned short* kq = Kp + rowbase * 1024 + hcol;
  const unsigned short* vq = Vp + rowbase * 1024 + hcol;

  bf16x8 qf[2][2];
#pragma unroll
  for (int qh = 0; qh < 2; ++qh) {
    const int qrow = qt * 128 + w * 32 + qh * 16 + lq;
#pragma unroll
    for (int kk = 0; kk < 2; ++kk)
      qf[qh][kk] = *(const bf16x8*)&Qp[(rowbase + qrow) * 1024 + hcol + kk * 32 + g * 8];
  }

  const float ks2 = 0.125f * 1.44269504088896f;
  float m0 = -1e30f, m1 = -1e30f, l0 = 0.f, l1 = 0.f;
  f32x4 oa[2][4] = {};
  unsigned short* Pw0 = Pl[w * 2];
  unsigned short* Pw1 = Pl[w * 2 + 1];
  const int pxor = (lq & 7) << 3;
  const int kxor = pxor;

  {
    gload_lds16(kq + (size_t)(c0 * 8 + srow) * 1024 + schunk * 8, &Ks[0][c0 * 512]);
    gload_lds16(kq + (size_t)(c1 * 8 + srow) * 1024 + schunk * 8, &Ks[0][c1 * 512]);
    gload_lds16(vq + (size_t)(c0 * 8 + vkeyl) * 1024 + vd0, &Vs[0][c0 * 512]);
    gload_lds16(vq + (size_t)(c1 * 8 + vkeyl) * 1024 + vd0, &Vs[0][c1 * 512]);
  }
  __syncthreads();

  for (int j = 0; j < 32; ++j) {
    const int cur = j & 1;
    if (j < 31) {
      const size_t so = (size_t)(j + 1) * 64 * 1024;
      gload_lds16(kq + so + (size_t)(c0 * 8 + srow) * 1024 + schunk * 8, &Ks[cur ^ 1][c0 * 512]);
      gload_lds16(kq + so + (size_t)(c1 * 8 + srow) * 1024 + schunk * 8, &Ks[cur ^ 1][c1 * 512]);
      gload_lds16(vq + so + (size_t)(c0 * 8 + vkeyl) * 1024 + vd0, &Vs[cur ^ 1][c0 * 512]);
      gload_lds16(vq + so + (size_t)(c1 * 8 + vkeyl) * 1024 + vd0, &Vs[cur ^ 1][c1 * 512]);
    }

    f32x4 cc[2][4];
#pragma unroll
    for (int qh = 0; qh < 2; ++qh)
#pragma unroll
      for (int t = 0; t < 4; ++t) cc[qh][t] = (f32x4){0.f, 0.f, 0.f, 0.f};
#pragma unroll
    for (int t = 0; t < 4; ++t) {
      const int rb = (t * 16 + lq) * 64;
#pragma unroll
      for (int kk = 0; kk < 2; ++kk) {
        bf16x8 kf = *(const bf16x8*)&Ks[cur][rb + ((kk * 32 + g * 8) ^ kxor)];
        cc[0][t] = __builtin_amdgcn_mfma_f32_16x16x32_bf16(kf, qf[0][kk], cc[0][t], 0, 0, 0);
        cc[1][t] = __builtin_amdgcn_mfma_f32_16x16x32_bf16(kf, qf[1][kk], cc[1][t], 0, 0, 0);
      }
    }

    float t0 = cc[0][0][0], t1 = cc[1][0][0];
#pragma unroll
    for (int t = 0; t < 4; ++t)
#pragma unroll
      for (int r = 0; r < 4; ++r) {
        t0 = fmaxf(t0, cc[0][t][r]);
        t1 = fmaxf(t1, cc[1][t][r]);
      }
    t0 = fmaxf(t0, __shfl_xor(t0, 16)); t0 = fmaxf(t0, __shfl_xor(t0, 32));
    t1 = fmaxf(t1, __shfl_xor(t1, 16)); t1 = fmaxf(t1, __shfl_xor(t1, 32));

    const int defer = (t0 - m0 <= 64.f) && (t1 - m1 <= 64.f);
    if (!__all(defer)) {
      float n0 = fmaxf(m0, t0), n1 = fmaxf(m1, t1);
      float cr0 = EXP2(ks2 * (m0 - n0)), cr1 = EXP2(ks2 * (m1 - n1));
      l0 *= cr0; l1 *= cr1;
#pragma unroll
      for (int dt = 0; dt < 4; ++dt) { oa[0][dt] *= cr0; oa[1][dt] *= cr1; }
      m0 = n0; m1 = n1;
    }
    const float mk0 = m0 * ks2, mk1 = m1 * ks2;
    float ps0 = 0.f, ps1 = 0.f;
#pragma unroll
    for (int t = 0; t < 4; ++t) {
      float a0 = EXP2(__builtin_fmaf(cc[0][t][0], ks2, -mk0));
      float a1 = EXP2(__builtin_fmaf(cc[0][t][1], ks2, -mk0));
      float a2 = EXP2(__builtin_fmaf(cc[0][t][2], ks2, -mk0));
      float a3 = EXP2(__builtin_fmaf(cc[0][t][3], ks2, -mk0));
      ps0 += (a0 + a1) + (a2 + a3);
      ushort4 pk0; pk0.x = bfu(a0); pk0.y = bfu(a1); pk0.z = bfu(a2); pk0.w = bfu(a3);
      *(ushort4*)&Pw0[lq * 64 + ((t * 16 + g * 4) ^ pxor)] = pk0;
      float b0 = EXP2(__builtin_fmaf(cc[1][t][0], ks2, -mk1));
      float b1 = EXP2(__builtin_fmaf(cc[1][t][1], ks2, -mk1));
      float b2 = EXP2(__builtin_fmaf(cc[1][t][2], ks2, -mk1));
      float b3 = EXP2(__builtin_fmaf(cc[1][t][3], ks2, -mk1));
      ps1 += (b0 + b1) + (b2 + b3);
      ushort4 pk1; pk1.x = bfu(b0); pk1.y = bfu(b1); pk1.z = bfu(b2); pk1.w = bfu(b3);
      *(ushort4*)&Pw1[lq * 64 + ((t * 16 + g * 4) ^ pxor)] = pk1;
    }
    l0 += ps0; l1 += ps1;

    bf16x8 pf[2][2];
#pragma unroll
    for (int qh = 0; qh < 2; ++qh) {
      unsigned short* Pw = qh ? Pw1 : Pw0;
#pragma unroll
      for (int kk = 0; kk < 2; ++kk)
        pf[qh][kk] = *(const bf16x8*)&Pw[lq * 64 + ((kk * 32 + g * 8) ^ pxor)];
    }
    const unsigned short* vb =
        &Vs[cur][g * 512 + ((lane >> 2) & 3) * 16 + (lane & 3) * 4];
    bf16x4 T[16];
    TRRD(T[0],  "0");    TRRD(T[1],  "128");  TRRD(T[2],  "256");  TRRD(T[3],  "384");
    TRRD(T[4],  "512");  TRRD(T[5],  "640");  TRRD(T[6],  "768");  TRRD(T[7],  "896");
    TRRD(T[8],  "4096"); TRRD(T[9],  "4224"); TRRD(T[10], "4352"); TRRD(T[11], "4480");
    TRRD(T[12], "4608"); TRRD(T[13], "4736"); TRRD(T[14], "4864"); TRRD(T[15], "4992");
    asm volatile("s_waitcnt lgkmcnt(0)" ::: "memory");
    __builtin_amdgcn_sched_barrier(0);
#pragma unroll
    for (int kk = 0; kk < 2; ++kk) {
#pragma unroll
      for (int dt = 0; dt < 4; ++dt) {
        bf16x8 vf = __builtin_shufflevector(T[kk * 8 + dt], T[kk * 8 + 4 + dt],
                                            0, 1, 2, 3, 4, 5, 6, 7);
        oa[0][dt] = __builtin_amdgcn_mfma_f32_16x16x32_bf16(vf, pf[0][kk], oa[0][dt], 0, 0, 0);
        oa[1][dt] = __builtin_amdgcn_mfma_f32_16x16x32_bf16(vf, pf[1][kk], oa[1][dt], 0, 0, 0);
      }
    }
    __syncthreads();
  }

  l0 += __shfl_xor(l0, 16); l0 += __shfl_xor(l0, 32);
  l1 += __shfl_xor(l1, 16); l1 += __shfl_xor(l1, 32);
  float inv0 = 1.0f / l0, inv1 = 1.0f / l1;
#pragma unroll
  for (int qh = 0; qh < 2; ++qh) {
    const float inv = qh ? inv1 : inv0;
    const int qrow = qt * 128 + w * 32 + qh * 16 + lq;
#pragma unroll
    for (int dt = 0; dt < 4; ++dt) {
      ushort4 pk;
      pk.x = bfu(oa[qh][dt][0] * inv);
      pk.y = bfu(oa[qh][dt][1] * inv);
      pk.z = bfu(oa[qh][dt][2] * inv);
      pk.w = bfu(oa[qh][dt][3] * inv);
      *(ushort4*)&Op[(rowbase + qrow) * 1024 + hcol + dt * 16 + g * 4] = pk;
    }
  }
}

// ------------------------- launcher --------------------------------------
extern "C" void kernel_launch(void* const* d_in, const int* in_sizes, int n_in,
                              void* d_out, int out_size, void* d_ws, size_t ws_size,
                              hipStream_t stream) {
  const float* q  = (const float*)d_in[0];
  const float* k  = (const float*)d_in[1];
  const float* v  = (const float*)d_in[2];
  const float* Wq = (const float*)d_in[3];
  const float* bq = (const float*)d_in[4];
  const float* Wk = (const float*)d_in[5];
  const float* bk = (const float*)d_in[6];
  const float* Wv = (const float*)d_in[7];
  const float* bv = (const float*)d_in[8];
  const float* Wo = (const float*)d_in[9];
  const float* bo = (const float*)d_in[10];

  unsigned short* ws = (unsigned short*)d_ws;
  const size_t SZ  = (size_t)8192 * 1024;
  const size_t WSZ = (size_t)1024 * 1024;
  unsigned short* Xq  = ws;            // Xq,Xk,Xv contiguous (TRIPLE A base)
  unsigned short* Wqb = Xq + 3 * SZ;   // Wq,Wk,Wv,Wo contiguous
  unsigned short* Qp  = Wqb + 4 * WSZ; // Qp,Kp,Vp contiguous (TRIPLE C base)
  unsigned short* Kp  = Qp + SZ;
  unsigned short* Vp  = Kp + SZ;
  unsigned short* Wob = Wqb + 3 * WSZ;
  unsigned short* At  = Xq;            // Xq dead after projections -> reuse

  cvt_all<<<(3 * BIGU + 4 * WU) / 256, 256, 0, stream>>>(q, k, v, Wq, Wk, Wv, Wo, (ushort4*)ws);

  gemm_bt<false, true><<<dim3(GN / 128, GM / 128, 3), 256, 0, stream>>>(Xq, Wqb, bq, bk, bv, Qp);

  attn_fwd<<<dim3(16, 64), 256, 0, stream>>>(Qp, Kp, Vp, At);

  gemm_bt<true, false><<<dim3(GN / 128, GM / 128, 1), 256, 0, stream>>>(At, Wob, bo, bo, bo, (float*)d_out);
}

// Round 4
// 341.455 us; speedup vs baseline: 1.2819x; 1.0362x over previous
//
#include <hip/hip_runtime.h>
#include <stdint.h>

typedef __bf16 bf16x8 __attribute__((ext_vector_type(8)));
typedef __bf16 bf16x4 __attribute__((ext_vector_type(4)));
typedef float f32x4 __attribute__((ext_vector_type(4)));

static __device__ __forceinline__ unsigned short f2bf(float f) {
  unsigned u = __builtin_bit_cast(unsigned, f);
  u += 0x7fffu + ((u >> 16) & 1u);   // RNE
  return (unsigned short)(u >> 16);
}

static __device__ __forceinline__ unsigned short bfu(float x) {
  __bf16 b = (__bf16)x;
  return __builtin_bit_cast(unsigned short, b);
}

#if __has_builtin(__builtin_amdgcn_exp2f)
#define EXP2(x) __builtin_amdgcn_exp2f(x)
#else
#define EXP2(x) __expf(0.69314718055994531f * (x))
#endif

static __device__ __forceinline__ void gload_lds16(const void* g, void* l) {
  __builtin_amdgcn_global_load_lds(
      (const __attribute__((address_space(1))) unsigned int*)(uintptr_t)g,
      (__attribute__((address_space(3))) unsigned int*)(uintptr_t)l, 16, 0, 0);
}

// ------------------------- fused fp32 -> bf16 convert (all 7 tensors) ----
#define BIGU 2097152
#define WU   262144
__global__ __launch_bounds__(256) void cvt_all(const float* __restrict__ q,  const float* __restrict__ k,
                                               const float* __restrict__ v,  const float* __restrict__ wq,
                                               const float* __restrict__ wk, const float* __restrict__ wv,
                                               const float* __restrict__ wo, ushort4* __restrict__ dst) {
  int u = blockIdx.x * 256 + threadIdx.x;
  const float4* src;
  if (u < BIGU)            src = (const float4*)q + u;
  else if (u < 2 * BIGU)   src = (const float4*)k + (u - BIGU);
  else if (u < 3 * BIGU)   src = (const float4*)v + (u - 2 * BIGU);
  else {
    int r = u - 3 * BIGU;
    if (r < WU)            src = (const float4*)wq + r;
    else if (r < 2 * WU)   src = (const float4*)wk + (r - WU);
    else if (r < 3 * WU)   src = (const float4*)wv + (r - 2 * WU);
    else                   src = (const float4*)wo + (r - 3 * WU);
  }
  float4 f = *src;
  ushort4 o;
  o.x = f2bf(f.x); o.y = f2bf(f.y); o.z = f2bf(f.z); o.w = f2bf(f.w);
  dst[u] = o;
}

// ------------------------- GEMM: C[M,N] = A[M,K] @ W[N,K]^T + bias ------
// 128x128 tile, BK=64, 2-phase double-buffered prefetch. TRIPLE: blockIdx.z
// picks one of the Q/K/V projection triples (contiguous A/W/C arrays).
#define GM 8192
#define GN 1024
#define GK 1024

template <bool OUTF32, bool TRIPLE>
__global__ __launch_bounds__(256, 2) void gemm_bt(const unsigned short* __restrict__ A0,
                                                  const unsigned short* __restrict__ W0,
                                                  const float* __restrict__ bias0,
                                                  const float* __restrict__ bias1,
                                                  const float* __restrict__ bias2,
                                                  void* __restrict__ Cout) {
  __shared__ unsigned short As[2][128 * 64];
  __shared__ unsigned short Bs[2][128 * 64];
  const int z = TRIPLE ? blockIdx.z : 0;
  const unsigned short* A  = A0 + (size_t)z * ((size_t)GM * GK);
  const unsigned short* Bw = W0 + (size_t)z * ((size_t)GN * GK);
  const float* bias = TRIPLE ? (z == 0 ? bias0 : (z == 1 ? bias1 : bias2)) : bias0;

  const int tid = threadIdx.x;
  const int w = tid >> 6;
  const int lane = tid & 63;
  const int lq = lane & 15;
  const int g = lane >> 4;
  const int bm = blockIdx.y * 128;
  const int bn = blockIdx.x * 128;
  const int srow = lane >> 3;
  const int schunk = (lane & 7) ^ srow;
  const int wrow = (w >> 1) * 64;
  const int wcol = (w & 1) * 64;

  f32x4 acc[4][4] = {};

#define STAGE(ktv, bufv)                                                                   \
  do {                                                                                     \
    _Pragma("unroll") for (int j = 0; j < 4; ++j) {                                        \
      const int r0 = w * 32 + j * 8;                                                       \
      gload_lds16(A  + (size_t)(bm + r0 + srow) * GK + (ktv) * 64 + schunk * 8,            \
                  &As[bufv][r0 * 64]);                                                     \
      gload_lds16(Bw + (size_t)(bn + r0 + srow) * GK + (ktv) * 64 + schunk * 8,            \
                  &Bs[bufv][r0 * 64]);                                                     \
    }                                                                                      \
  } while (0)

  STAGE(0, 0);
  __syncthreads();

  for (int kt = 0; kt < GK / 64; ++kt) {
    const int cur = kt & 1;
    if (kt < GK / 64 - 1) STAGE(kt + 1, cur ^ 1);   // prefetch next tile

#pragma unroll
    for (int kk = 0; kk < 2; ++kk) {
      bf16x8 af[4], bfv[4];
#pragma unroll
      for (int mt = 0; mt < 4; ++mt) {
        int m = wrow + mt * 16 + lq;
        af[mt] = *(const bf16x8*)&As[cur][m * 64 + ((kk * 32 + g * 8) ^ ((m & 7) << 3))];
      }
#pragma unroll
      for (int nt = 0; nt < 4; ++nt) {
        int n = wcol + nt * 16 + lq;
        bfv[nt] = *(const bf16x8*)&Bs[cur][n * 64 + ((kk * 32 + g * 8) ^ ((n & 7) << 3))];
      }
#pragma unroll
      for (int mt = 0; mt < 4; ++mt)
#pragma unroll
        for (int nt = 0; nt < 4; ++nt)
          acc[mt][nt] = __builtin_amdgcn_mfma_f32_16x16x32_bf16(af[mt], bfv[nt], acc[mt][nt], 0, 0, 0);
    }
    __syncthreads();   // drains prefetch vmcnt AFTER compute; guards buffer reuse
  }
#undef STAGE

  float bvs[4];
#pragma unroll
  for (int nt = 0; nt < 4; ++nt) bvs[nt] = bias[bn + wcol + nt * 16 + lq];

#pragma unroll
  for (int mt = 0; mt < 4; ++mt) {
#pragma unroll
    for (int nt = 0; nt < 4; ++nt) {
#pragma unroll
      for (int r = 0; r < 4; ++r) {
        int m = bm + wrow + mt * 16 + g * 4 + r;
        int n = bn + wcol + nt * 16 + lq;
        float v = acc[mt][nt][r] + bvs[nt];
        if (OUTF32) ((float*)Cout)[(size_t)m * GN + n] = v;
        else ((unsigned short*)Cout)[(size_t)z * ((size_t)GM * GN) + (size_t)m * GN + n] = f2bf(v);
      }
    }
  }
}

// ------------------------- flash attention v3: 4 q-halves per wave --------
// grid (8 q-tiles of 256 rows, 64 bh), 256 threads = 4 waves, each wave 64
// q-rows as four 16-row halves sharing every K-fragment and V tr_read.
// KVB=64, double-buffered K (row-swizzled) and V (tr16-subtiled) staged via
// global_load_lds with pre-swizzled source. Swapped QK^T; PV via
// ds_read_b64_tr_b16; per-(wave,qh) P LDS round trip; defer-max THR=64 raw.
#define TRRD(dst, off) \
  asm volatile("ds_read_b64_tr_b16 %0, %1 offset:" off \
               : "=v"(dst) \
               : "v"((const __attribute__((address_space(3))) unsigned short*)(uintptr_t)vb))

__global__ __launch_bounds__(256, 2) void attn_fwd(const unsigned short* __restrict__ Qp,
                                                   const unsigned short* __restrict__ Kp,
                                                   const unsigned short* __restrict__ Vp,
                                                   unsigned short* __restrict__ Op) {
  __shared__ unsigned short Ks[2][4096];    // 16 KB
  __shared__ unsigned short Vs[2][4096];    // 16 KB
  __shared__ unsigned short Pl[16][1024];   // 32 KB: (wave, qh) private
  const int tid = threadIdx.x;
  const int w = tid >> 6;
  const int lane = tid & 63;
  const int lq = lane & 15;
  const int g = lane >> 4;
  const int qt = blockIdx.x;
  const int bh = blockIdx.y;
  const int b = bh >> 4;
  const int h = bh & 15;
  const size_t rowbase = (size_t)b * 2048;
  const int hcol = h * 64;

  const int c0 = w * 2, c1 = w * 2 + 1;
  const int srow = lane >> 3;
  const int schunk = (lane & 7) ^ srow;
  const int vkeyl = (lane >> 5) * 4 + ((lane >> 1) & 3);
  const int vd0   = ((lane >> 3) & 3) * 16 + (lane & 1) * 8;

  const unsigned short* kq = Kp + rowbase * 1024 + hcol;
  const unsigned short* vq = Vp + rowbase * 1024 + hcol;

  // Q fragments: four q-halves (wave owns rows qt*256 + w*64 .. +63)
  bf16x8 qf[4][2];
#pragma unroll
  for (int qh = 0; qh < 4; ++qh) {
    const int qrow = qt * 256 + w * 64 + qh * 16 + lq;
#pragma unroll
    for (int kk = 0; kk < 2; ++kk)
      qf[qh][kk] = *(const bf16x8*)&Qp[(rowbase + qrow) * 1024 + hcol + kk * 32 + g * 8];
  }

  const float ks2 = 0.125f * 1.44269504088896f;  // scale * log2(e)
  float mr[4] = {-1e30f, -1e30f, -1e30f, -1e30f};
  float lr[4] = {0.f, 0.f, 0.f, 0.f};
  f32x4 oa[4][4] = {};
  const int pxor = (lq & 7) << 3;                // P swizzle (lane const)
  const int kxor = pxor;                         // K row swizzle (krow&7 == lq&7)

  // prologue: stage tile 0 into buf 0
  gload_lds16(kq + (size_t)(c0 * 8 + srow) * 1024 + schunk * 8, &Ks[0][c0 * 512]);
  gload_lds16(kq + (size_t)(c1 * 8 + srow) * 1024 + schunk * 8, &Ks[0][c1 * 512]);
  gload_lds16(vq + (size_t)(c0 * 8 + vkeyl) * 1024 + vd0, &Vs[0][c0 * 512]);
  gload_lds16(vq + (size_t)(c1 * 8 + vkeyl) * 1024 + vd0, &Vs[0][c1 * 512]);
  __syncthreads();

  for (int j = 0; j < 32; ++j) {
    const int cur = j & 1;
    if (j < 31) {   // prefetch next tile into other buffer
      const size_t so = (size_t)(j + 1) * 64 * 1024;
      gload_lds16(kq + so + (size_t)(c0 * 8 + srow) * 1024 + schunk * 8, &Ks[cur ^ 1][c0 * 512]);
      gload_lds16(kq + so + (size_t)(c1 * 8 + srow) * 1024 + schunk * 8, &Ks[cur ^ 1][c1 * 512]);
      gload_lds16(vq + so + (size_t)(c0 * 8 + vkeyl) * 1024 + vd0, &Vs[cur ^ 1][c0 * 512]);
      gload_lds16(vq + so + (size_t)(c1 * 8 + vkeyl) * 1024 + vd0, &Vs[cur ^ 1][c1 * 512]);
    }

    // ---- QK^T: kf shared across all 4 q-halves
    f32x4 cc[4][4];
#pragma unroll
    for (int qh = 0; qh < 4; ++qh)
#pragma unroll
      for (int t = 0; t < 4; ++t) cc[qh][t] = (f32x4){0.f, 0.f, 0.f, 0.f};
    __builtin_amdgcn_s_setprio(1);
#pragma unroll
    for (int t = 0; t < 4; ++t) {
      const int rb = (t * 16 + lq) * 64;
#pragma unroll
      for (int kk = 0; kk < 2; ++kk) {
        bf16x8 kf = *(const bf16x8*)&Ks[cur][rb + ((kk * 32 + g * 8) ^ kxor)];
#pragma unroll
        for (int qh = 0; qh < 4; ++qh)
          cc[qh][t] = __builtin_amdgcn_mfma_f32_16x16x32_bf16(kf, qf[qh][kk], cc[qh][t], 0, 0, 0);
      }
    }
    __builtin_amdgcn_s_setprio(0);

    // ---- online softmax (raw scores; scale folded into exp2)
    float tm[4];
#pragma unroll
    for (int qh = 0; qh < 4; ++qh) {
      float t0 = cc[qh][0][0];
#pragma unroll
      for (int t = 0; t < 4; ++t)
#pragma unroll
        for (int r = 0; r < 4; ++r) t0 = fmaxf(t0, cc[qh][t][r]);
      t0 = fmaxf(t0, __shfl_xor(t0, 16));
      t0 = fmaxf(t0, __shfl_xor(t0, 32));
      tm[qh] = t0;
    }
    int defer = 1;
#pragma unroll
    for (int qh = 0; qh < 4; ++qh) defer &= (tm[qh] - mr[qh] <= 64.f);
    if (!__all(defer)) {
#pragma unroll
      for (int qh = 0; qh < 4; ++qh) {
        float n = fmaxf(mr[qh], tm[qh]);
        float cr = EXP2(ks2 * (mr[qh] - n));
        lr[qh] *= cr;
#pragma unroll
        for (int dt = 0; dt < 4; ++dt) oa[qh][dt] *= cr;
        mr[qh] = n;
      }
    }
#pragma unroll
    for (int qh = 0; qh < 4; ++qh) {
      const float mk = mr[qh] * ks2;
      float ps = 0.f;
      unsigned short* Pw = Pl[w * 4 + qh];
#pragma unroll
      for (int t = 0; t < 4; ++t) {
        float a0 = EXP2(__builtin_fmaf(cc[qh][t][0], ks2, -mk));
        float a1 = EXP2(__builtin_fmaf(cc[qh][t][1], ks2, -mk));
        float a2 = EXP2(__builtin_fmaf(cc[qh][t][2], ks2, -mk));
        float a3 = EXP2(__builtin_fmaf(cc[qh][t][3], ks2, -mk));
        ps += (a0 + a1) + (a2 + a3);
        ushort4 pk;
        pk.x = bfu(a0); pk.y = bfu(a1); pk.z = bfu(a2); pk.w = bfu(a3);
        *(ushort4*)&Pw[lq * 64 + ((t * 16 + g * 4) ^ pxor)] = pk;
      }
      lr[qh] += ps;
    }

    // ---- PV: V tr_reads shared across all 4 q-halves
    bf16x8 pf[4][2];
#pragma unroll
    for (int qh = 0; qh < 4; ++qh) {
      unsigned short* Pw = Pl[w * 4 + qh];
#pragma unroll
      for (int kk = 0; kk < 2; ++kk)
        pf[qh][kk] = *(const bf16x8*)&Pw[lq * 64 + ((kk * 32 + g * 8) ^ pxor)];
    }
    const unsigned short* vb =
        &Vs[cur][g * 512 + ((lane >> 2) & 3) * 16 + (lane & 3) * 4];
    bf16x4 T[16];
    TRRD(T[0],  "0");    TRRD(T[1],  "128");  TRRD(T[2],  "256");  TRRD(T[3],  "384");
    TRRD(T[4],  "512");  TRRD(T[5],  "640");  TRRD(T[6],  "768");  TRRD(T[7],  "896");
    TRRD(T[8],  "4096"); TRRD(T[9],  "4224"); TRRD(T[10], "4352"); TRRD(T[11], "4480");
    TRRD(T[12], "4608"); TRRD(T[13], "4736"); TRRD(T[14], "4864"); TRRD(T[15], "4992");
    asm volatile("s_waitcnt lgkmcnt(0)" ::: "memory");
    __builtin_amdgcn_sched_barrier(0);
    __builtin_amdgcn_s_setprio(1);
#pragma unroll
    for (int kk = 0; kk < 2; ++kk) {
#pragma unroll
      for (int dt = 0; dt < 4; ++dt) {
        bf16x8 vf = __builtin_shufflevector(T[kk * 8 + dt], T[kk * 8 + 4 + dt],
                                            0, 1, 2, 3, 4, 5, 6, 7);
#pragma unroll
        for (int qh = 0; qh < 4; ++qh)
          oa[qh][dt] = __builtin_amdgcn_mfma_f32_16x16x32_bf16(vf, pf[qh][kk], oa[qh][dt], 0, 0, 0);
      }
    }
    __builtin_amdgcn_s_setprio(0);
    __syncthreads();
  }

  // ---- epilogue
#pragma unroll
  for (int qh = 0; qh < 4; ++qh) {
    float l = lr[qh];
    l += __shfl_xor(l, 16);
    l += __shfl_xor(l, 32);
    const float inv = 1.0f / l;
    const int qrow = qt * 256 + w * 64 + qh * 16 + lq;
#pragma unroll
    for (int dt = 0; dt < 4; ++dt) {
      ushort4 pk;
      pk.x = bfu(oa[qh][dt][0] * inv);
      pk.y = bfu(oa[qh][dt][1] * inv);
      pk.z = bfu(oa[qh][dt][2] * inv);
      pk.w = bfu(oa[qh][dt][3] * inv);
      *(ushort4*)&Op[(rowbase + qrow) * 1024 + hcol + dt * 16 + g * 4] = pk;
    }
  }
}

// ------------------------- launcher --------------------------------------
extern "C" void kernel_launch(void* const* d_in, const int* in_sizes, int n_in,
                              void* d_out, int out_size, void* d_ws, size_t ws_size,
                              hipStream_t stream) {
  const float* q  = (const float*)d_in[0];
  const float* k  = (const float*)d_in[1];
  const float* v  = (const float*)d_in[2];
  const float* Wq = (const float*)d_in[3];
  const float* bq = (const float*)d_in[4];
  const float* Wk = (const float*)d_in[5];
  const float* bk = (const float*)d_in[6];
  const float* Wv = (const float*)d_in[7];
  const float* bv = (const float*)d_in[8];
  const float* Wo = (const float*)d_in[9];
  const float* bo = (const float*)d_in[10];

  unsigned short* ws = (unsigned short*)d_ws;
  const size_t SZ  = (size_t)8192 * 1024;
  const size_t WSZ = (size_t)1024 * 1024;
  unsigned short* Xq  = ws;            // Xq,Xk,Xv contiguous (TRIPLE A base)
  unsigned short* Wqb = Xq + 3 * SZ;   // Wq,Wk,Wv,Wo contiguous
  unsigned short* Qp  = Wqb + 4 * WSZ; // Qp,Kp,Vp contiguous (TRIPLE C base)
  unsigned short* Kp  = Qp + SZ;
  unsigned short* Vp  = Kp + SZ;
  unsigned short* Wob = Wqb + 3 * WSZ;
  unsigned short* At  = Xq;            // Xq dead after projections -> reuse

  cvt_all<<<(3 * BIGU + 4 * WU) / 256, 256, 0, stream>>>(q, k, v, Wq, Wk, Wv, Wo, (ushort4*)ws);

  gemm_bt<false, true><<<dim3(GN / 128, GM / 128, 3), 256, 0, stream>>>(Xq, Wqb, bq, bk, bv, Qp);

  attn_fwd<<<dim3(8, 64), 256, 0, stream>>>(Qp, Kp, Vp, At);

  gemm_bt<true, false><<<dim3(GN / 128, GM / 128, 1), 256, 0, stream>>>(At, Wob, bo, bo, bo, (float*)d_out);
}